// Round 3
// baseline (244.249 us; speedup 1.0000x reference)
//
#include <hip/hip_runtime.h>

#define TPB    256
#define SLICE  512
#define MAXB   8
#define GRP    8

static inline int cdiv(int a, int b) { return (a + b - 1) / b; }

// --- hot-loop helpers -------------------------------------------------------

__device__ __forceinline__ void load_grp(float4* dst, const float4* pts, int g) {
#pragma unroll
    for (int u = 0; u < GRP; ++u) dst[u] = pts[g + u];
}

__device__ __forceinline__ void proc_grp(const float4* buf, const float* xs, int g,
                                         float ox, float oy, float oz, float r2,
                                         float& cnt, float* sacc) {
    float d2[GRP];
#pragma unroll
    for (int u = 0; u < GRP; ++u) {
        const float dx = ox - buf[u].x;
        const float dy = oy - buf[u].y;
        const float dz = oz - buf[u].z;
        d2[u] = dx * dx + dy * dy + dz * dz;
    }
    const float m = fminf(fminf(fminf(d2[0], d2[1]), fminf(d2[2], d2[3])),
                          fminf(fminf(d2[4], d2[5]), fminf(d2[6], d2[7])));
    if (m <= r2) {                       // wave-taken ~23% of groups
#pragma unroll
        for (int u = 0; u < GRP; ++u) {
            if (d2[u] <= r2) {
                cnt += 1.0f;
#pragma unroll
                for (int b = 0; b < MAXB; ++b)
                    sacc[b] += xs[b * SLICE + g + u];   // xs zero for b>=B
            }
        }
    }
}

// --- main kernel ------------------------------------------------------------
// mode 0: write per-slice partials (finalize in separate kernel)
// mode 1: partials + fused last-block finalize (ticket in flags[])
// mode 2: atomic accumulate into cnt[n_out] + sum[B][n_out] (pre-zeroed)
__global__ void __launch_bounds__(TPB) ball_main(
    const float* __restrict__ x,        // [B, n_in]
    const float* __restrict__ inp_pos,  // [n_in, 3]
    const float* __restrict__ out_pos,  // [n_out, 3]
    float* __restrict__ psum,           // mode<2: [S][B][n_out]; mode2: [B][n_out]
    float* __restrict__ pcnt,           // mode<2: [S][n_out];    mode2: [n_out]
    int*   __restrict__ flags,          // mode1: [gridDim.x], zeroed
    float* __restrict__ out,            // mode1 only
    int B, int n_in, int n_out, float r2, int S, int mode)
{
    __shared__ float4 pts[SLICE + 2 * GRP];
    __shared__ float  xs[MAXB * SLICE];
    __shared__ int    ticket;

    const int s    = blockIdx.y;
    const int base = s * SLICE;

    // Stage positions (sentinel-padded so the pipelined prefetch never needs a guard)
    for (int j = (int)threadIdx.x; j < SLICE + 2 * GRP; j += TPB) {
        float4 v = make_float4(1e9f, 1e9f, 1e9f, 0.0f);
        const int g = base + j;
        if (j < SLICE && g < n_in)
            v = make_float4(inp_pos[3 * g], inp_pos[3 * g + 1], inp_pos[3 * g + 2], 0.0f);
        pts[j] = v;
    }
    // Stage x slice [b][j] (zeros for b >= B)
    for (int t = (int)threadIdx.x; t < (MAXB * SLICE) / 4; t += TPB) {
        const int b  = t / (SLICE / 4);
        const int j4 = (t % (SLICE / 4)) * 4;
        float4 v = make_float4(0.0f, 0.0f, 0.0f, 0.0f);
        if (b < B && base + j4 + 3 < n_in)
            v = *(const float4*)(x + (size_t)b * n_in + base + j4);
        *(float4*)(xs + b * SLICE + j4) = v;
    }
    __syncthreads();

    const int ob = blockIdx.x;
    const int o  = ob * TPB + (int)threadIdx.x;
    float ox = 1e9f, oy = 1e9f, oz = 1e9f;       // sentinel for OOB lanes
    if (o < n_out) {
        ox = out_pos[3 * o];
        oy = out_pos[3 * o + 1];
        oz = out_pos[3 * o + 2];
    }

    float cnt = 0.0f;
    float sacc[MAXB];
#pragma unroll
    for (int b = 0; b < MAXB; ++b) sacc[b] = 0.0f;

    // Software-pipelined: ping-pong register buffers so group g+1's LDS reads
    // issue before group g's compute (covers ~120-cyc LDS latency per-wave).
    float4 A[GRP], Bb[GRP];
    load_grp(A, pts, 0);
    for (int g = 0; g < SLICE; g += 2 * GRP) {
        load_grp(Bb, pts, g + GRP);
        proc_grp(A, xs, g, ox, oy, oz, r2, cnt, sacc);
        load_grp(A, pts, g + 2 * GRP);           // pad region at the tail
        proc_grp(Bb, xs, g + GRP, ox, oy, oz, r2, cnt, sacc);
    }

    // --- epilogue ---
    if (mode == 2) {
        if (o < n_out) {
            unsafeAtomicAdd(pcnt + o, cnt);
#pragma unroll
            for (int b = 0; b < MAXB; ++b)
                if (b < B) unsafeAtomicAdd(psum + (size_t)b * n_out + o, sacc[b]);
        }
        return;
    }

    const size_t sbo = (size_t)s * B * n_out;
    if (o < n_out) {
        pcnt[(size_t)s * n_out + o] = cnt;
#pragma unroll
        for (int b = 0; b < MAXB; ++b)
            if (b < B) psum[sbo + (size_t)b * n_out + o] = sacc[b];
    }
    if (mode != 1) return;

    // Fused finalize: last block to finish this out-column reduces it.
    __threadfence();
    if (threadIdx.x == 0) ticket = atomicAdd(flags + ob, 1);
    __syncthreads();
    if (ticket == S - 1) {
        __threadfence();
        if (o < n_out) {
            float c = 0.0f;
            for (int k = 0; k < S; ++k) c += pcnt[(size_t)k * n_out + o];
            const float cc = (c > 0.0f) ? c : 1.0f;
#pragma unroll
            for (int b = 0; b < MAXB; ++b) {
                if (b < B) {
                    float a = 0.0f;
                    for (int k = 0; k < S; ++k)
                        a += psum[(size_t)k * B * n_out + (size_t)b * n_out + o];
                    out[(size_t)b * n_out + o] = a / cc;
                }
            }
        }
    }
}

// --- fallback finalize kernels ---------------------------------------------

__global__ void __launch_bounds__(TPB) final_partials(
    const float* __restrict__ ws, float* __restrict__ out, int B, int n_out, int S)
{
    const int i = blockIdx.x * TPB + (int)threadIdx.x;
    if (i >= B * n_out) return;
    const int o = i % n_out;
    const float* psum = ws;
    const float* pcnt = ws + (size_t)S * B * n_out;
    float acc = 0.0f, c = 0.0f;
    for (int k = 0; k < S; ++k) {
        acc += psum[(size_t)k * B * n_out + i];
        c   += pcnt[(size_t)k * n_out + o];
    }
    out[i] = acc / (c > 0.0f ? c : 1.0f);
}

__global__ void __launch_bounds__(TPB) final_atomic(
    const float* __restrict__ ws, float* __restrict__ out, int B, int n_out)
{
    const int i = blockIdx.x * TPB + (int)threadIdx.x;
    if (i >= B * n_out) return;
    const float c = ws[n_out * (size_t)B + (i % n_out)];
    out[i] = ws[i] / (c > 0.0f ? c : 1.0f);
}

// --- host -------------------------------------------------------------------

extern "C" void kernel_launch(void* const* d_in, const int* in_sizes, int n_in_args,
                              void* d_out, int out_size, void* d_ws, size_t ws_size,
                              hipStream_t stream) {
    const float* x  = (const float*)d_in[0];
    const float* ip = (const float*)d_in[1];
    const float* op = (const float*)d_in[2];
    float* out = (float*)d_out;

    const int n_in  = in_sizes[1] / 3;
    const int n_out = in_sizes[2] / 3;
    const int B     = in_sizes[0] / n_in;

    const int S  = cdiv(n_in, SLICE);
    const int gx = cdiv(n_out, TPB);
    const float r2 = (float)(0.05 * 0.05);

    const size_t need_part  = (size_t)S * (B + 1) * n_out * sizeof(float);
    const size_t need_fused = need_part + (size_t)gx * sizeof(int);

    float* psum = (float*)d_ws;                               // [S][B][n_out]
    float* pcnt = psum + (size_t)S * B * n_out;               // [S][n_out]
    dim3 grid(gx, S);

    if (ws_size >= need_fused) {
        int* flags = (int*)((char*)d_ws + need_part);
        hipMemsetAsync(flags, 0, (size_t)gx * sizeof(int), stream);
        ball_main<<<grid, TPB, 0, stream>>>(x, ip, op, psum, pcnt, flags, out,
                                            B, n_in, n_out, r2, S, 1);
    } else if (ws_size >= need_part) {
        ball_main<<<grid, TPB, 0, stream>>>(x, ip, op, psum, pcnt, nullptr, out,
                                            B, n_in, n_out, r2, S, 0);
        final_partials<<<cdiv(B * n_out, TPB), TPB, 0, stream>>>(
            (const float*)d_ws, out, B, n_out, S);
    } else {
        // atomic fallback: sum[B][n_out] then cnt[n_out]
        float* sum = (float*)d_ws;
        float* cnt = sum + (size_t)B * n_out;
        hipMemsetAsync(d_ws, 0, (size_t)(B + 1) * n_out * sizeof(float), stream);
        ball_main<<<grid, TPB, 0, stream>>>(x, ip, op, sum, cnt, nullptr, out,
                                            B, n_in, n_out, r2, S, 2);
        final_atomic<<<cdiv(B * n_out, TPB), TPB, 0, stream>>>(
            (const float*)d_ws, out, B, n_out);
    }
}

// Round 4
// 120.299 us; speedup vs baseline: 2.0303x; 2.0303x over previous
//
#include <hip/hip_runtime.h>

#define TPB  256
#define MAXB 8
#define UNR  4

static inline int cdiv(int a, int b) { return (a + b - 1) / b; }
static inline int rndup(int a, int b) { return cdiv(a, b) * b; }

// --- pack: packed[i]=(px,py,pz,0) sentinel-padded; xT[i][0..7] transposed x --
__global__ void __launch_bounds__(TPB) pack_kernel(
    const float* __restrict__ x, const float* __restrict__ ip,
    float4* __restrict__ packed, float* __restrict__ xT,
    int B, int n_in, int n_pad)
{
    const int i = blockIdx.x * TPB + (int)threadIdx.x;
    if (i >= n_pad) return;
    float4 v = make_float4(1e9f, 1e9f, 1e9f, 0.0f);   // sentinel: never hits
    if (i < n_in)
        v = make_float4(ip[3 * i], ip[3 * i + 1], ip[3 * i + 2], 0.0f);
    packed[i] = v;
    if (i < n_in) {
        float xv[MAXB];
#pragma unroll
        for (int b = 0; b < MAXB; ++b) xv[b] = (b < B) ? x[(size_t)b * n_in + i] : 0.0f;
        float4* dst = (float4*)(xT + (size_t)i * MAXB);
        dst[0] = make_float4(xv[0], xv[1], xv[2], xv[3]);
        dst[1] = make_float4(xv[4], xv[5], xv[6], xv[7]);
    }
}

// --- main: no LDS. Point loads are wave-uniform (loop-indexed) -> scalar/SMEM
// path (s_load_dwordx4); hit gathers read xT at uniform addresses (L2-hot).
// mode 0: per-slice partials; mode 1: atomic accumulate (pre-zeroed).
__global__ void __launch_bounds__(TPB) ball_main(
    const float4* __restrict__ packed,   // [S*L]
    const float*  __restrict__ xT,       // [n_in][8]
    const float*  __restrict__ out_pos,  // [n_out][3]
    float* __restrict__ psum,            // mode0: [S][B][n_out]; mode1: [B][n_out]
    float* __restrict__ pcnt,            // mode0: [S][n_out];    mode1: [n_out]
    int B, int n_out, int L, float r2, int atomic_mode)
{
    const int s = blockIdx.y;
    const int o = blockIdx.x * TPB + (int)threadIdx.x;

    float ox = 1e9f, oy = 1e9f, oz = 1e9f;   // OOB lanes never match
    if (o < n_out) {
        ox = out_pos[3 * o];
        oy = out_pos[3 * o + 1];
        oz = out_pos[3 * o + 2];
    }

    const float4* __restrict__ pp = packed + (size_t)s * L;

    float cnt = 0.0f;
    float sacc[MAXB];
#pragma unroll
    for (int b = 0; b < MAXB; ++b) sacc[b] = 0.0f;

    for (int j = 0; j < L; j += UNR) {
        float d2[UNR];
#pragma unroll
        for (int u = 0; u < UNR; ++u) {
            const float4 p = pp[j + u];
            // identical expression to the validated R1 kernel (membership bits)
            const float dx = ox - p.x;
            const float dy = oy - p.y;
            const float dz = oz - p.z;
            d2[u] = dx * dx + dy * dy + dz * dz;
        }
        const float m = fminf(fminf(d2[0], d2[1]), fminf(d2[2], d2[3]));
        if (m <= r2) {                         // wave-taken ~12% of groups
#pragma unroll
            for (int u = 0; u < UNR; ++u) {
                if (d2[u] <= r2) {
                    cnt += 1.0f;
                    const size_t gi = (size_t)s * L + j + u;   // < n_in when hit
                    const float4* xv = (const float4*)(xT + gi * MAXB);
                    const float4 a = xv[0], b4 = xv[1];
                    sacc[0] += a.x;  sacc[1] += a.y;
                    sacc[2] += a.z;  sacc[3] += a.w;
                    sacc[4] += b4.x; sacc[5] += b4.y;
                    sacc[6] += b4.z; sacc[7] += b4.w;
                }
            }
        }
    }

    if (o >= n_out) return;
    if (atomic_mode) {
        unsafeAtomicAdd(pcnt + o, cnt);
#pragma unroll
        for (int b = 0; b < MAXB; ++b)
            if (b < B) unsafeAtomicAdd(psum + (size_t)b * n_out + o, sacc[b]);
    } else {
        pcnt[(size_t)s * n_out + o] = cnt;
#pragma unroll
        for (int b = 0; b < MAXB; ++b)
            if (b < B) psum[((size_t)s * B + b) * n_out + o] = sacc[b];
    }
}

// --- finalize ----------------------------------------------------------------
__global__ void __launch_bounds__(TPB) final_partials(
    const float* __restrict__ psum, const float* __restrict__ pcnt,
    float* __restrict__ out, int B, int n_out, int S)
{
    const int i = blockIdx.x * TPB + (int)threadIdx.x;
    if (i >= B * n_out) return;
    const int b = i / n_out;
    const int o = i - b * n_out;
    float acc = 0.0f, c = 0.0f;
    for (int k = 0; k < S; ++k) {
        acc += psum[((size_t)k * B + b) * n_out + o];
        c   += pcnt[(size_t)k * n_out + o];
    }
    out[i] = acc / (c > 0.0f ? c : 1.0f);
}

__global__ void __launch_bounds__(TPB) final_atomic(
    const float* __restrict__ sum, const float* __restrict__ cnt,
    float* __restrict__ out, int B, int n_out)
{
    const int i = blockIdx.x * TPB + (int)threadIdx.x;
    if (i >= B * n_out) return;
    const float c = cnt[i % n_out];
    out[i] = sum[i] / (c > 0.0f ? c : 1.0f);
}

// --- host --------------------------------------------------------------------
extern "C" void kernel_launch(void* const* d_in, const int* in_sizes, int n_in_args,
                              void* d_out, int out_size, void* d_ws, size_t ws_size,
                              hipStream_t stream) {
    const float* x  = (const float*)d_in[0];
    const float* ip = (const float*)d_in[1];
    const float* op = (const float*)d_in[2];
    float* out = (float*)d_out;

    const int n_in  = in_sizes[1] / 3;
    const int n_out = in_sizes[2] / 3;
    const int B     = in_sizes[0] / n_in;
    const float r2  = (float)(0.05 * 0.05);
    const int gx    = cdiv(n_out, TPB);

    // Pick largest S whose partial buffers fit the workspace.
    int S = 0, L = 0;
    size_t base_bytes = 0;
    const int cand[3] = {64, 32, 16};
    for (int c = 0; c < 3; ++c) {
        const int Sc = cand[c];
        const int Lc = rndup(cdiv(n_in, Sc), UNR);
        const int n_pad = Sc * Lc;
        const size_t bytes = (size_t)n_pad * 16           // packed
                           + (size_t)n_in * MAXB * 4      // xT
                           + (size_t)Sc * (B + 1) * n_out * 4;
        if (ws_size >= bytes) { S = Sc; L = Lc; base_bytes = (size_t)n_pad * 16; break; }
    }

    if (S > 0) {
        const int n_pad = S * L;
        float4* packed = (float4*)d_ws;
        float*  xT     = (float*)((char*)d_ws + base_bytes);
        float*  psum   = xT + (size_t)n_in * MAXB;        // [S][B][n_out]
        float*  pcnt   = psum + (size_t)S * B * n_out;    // [S][n_out]

        pack_kernel<<<cdiv(n_pad, TPB), TPB, 0, stream>>>(x, ip, packed, xT,
                                                          B, n_in, n_pad);
        dim3 grid(gx, S);
        ball_main<<<grid, TPB, 0, stream>>>(packed, xT, op, psum, pcnt,
                                            B, n_out, L, r2, 0);
        final_partials<<<cdiv(B * n_out, TPB), TPB, 0, stream>>>(
            psum, pcnt, out, B, n_out, S);
    } else {
        // Small-ws fallback: atomic accumulate.
        const int Sa = 64;
        const int La = rndup(cdiv(n_in, Sa), UNR);
        const int n_pad = Sa * La;
        float4* packed = (float4*)d_ws;
        float*  xT     = (float*)((char*)d_ws + (size_t)n_pad * 16);
        float*  sum    = xT + (size_t)n_in * MAXB;        // [B][n_out]
        float*  cnt    = sum + (size_t)B * n_out;         // [n_out]

        hipMemsetAsync(sum, 0, (size_t)(B + 1) * n_out * sizeof(float), stream);
        pack_kernel<<<cdiv(n_pad, TPB), TPB, 0, stream>>>(x, ip, packed, xT,
                                                          B, n_in, n_pad);
        dim3 grid(gx, Sa);
        ball_main<<<grid, TPB, 0, stream>>>(packed, xT, op, sum, cnt,
                                            B, n_out, La, r2, 1);
        final_atomic<<<cdiv(B * n_out, TPB), TPB, 0, stream>>>(
            sum, cnt, out, B, n_out);
    }
}

// Round 5
// 71.984 us; speedup vs baseline: 3.3931x; 1.6712x over previous
//
#include <hip/hip_runtime.h>

#define TPB   256
#define MAXB  8
#define GD    20
#define NC    (GD * GD * GD)
#define CAP   32

static inline int cdiv(int a, int b) { return (a + b - 1) / b; }

// --- bin + transpose kernel --------------------------------------------------
// bins[cell][slot] = (px,py,pz, bitcast(i)); xT[i][0..7] = x[b][i] (0 for b>=B)
__global__ void __launch_bounds__(TPB) bin_kernel(
    const float* __restrict__ x, const float* __restrict__ ip,
    int* __restrict__ counts, float4* __restrict__ bins,
    float* __restrict__ xT, int B, int n_in)
{
    const int i = blockIdx.x * TPB + (int)threadIdx.x;
    if (i >= n_in) return;
    const float px = ip[3 * i], py = ip[3 * i + 1], pz = ip[3 * i + 2];
    const int cx = min(GD - 1, max(0, (int)(px * (float)GD)));
    const int cy = min(GD - 1, max(0, (int)(py * (float)GD)));
    const int cz = min(GD - 1, max(0, (int)(pz * (float)GD)));
    const int cell = (cx * GD + cy) * GD + cz;
    const int slot = atomicAdd(counts + cell, 1);
    if (slot < CAP)   // P(count>32) ~ 0 at lambda=2.05; query clamps to CAP
        bins[(size_t)cell * CAP + slot] = make_float4(px, py, pz, __int_as_float(i));
    float v[MAXB];
#pragma unroll
    for (int b = 0; b < MAXB; ++b)
        v[b] = (b < B) ? x[(size_t)b * n_in + i] : 0.0f;
    float4* dst = (float4*)(xT + (size_t)i * MAXB);
    dst[0] = make_float4(v[0], v[1], v[2], v[3]);
    dst[1] = make_float4(v[4], v[5], v[6], v[7]);
}

// --- query kernel: one wave per output point --------------------------------
__global__ void __launch_bounds__(TPB) query_kernel(
    const int* __restrict__ counts, const float4* __restrict__ bins,
    const float* __restrict__ xT, const float* __restrict__ out_pos,
    float* __restrict__ out, int B, int n_out, float r2)
{
    const int lane = (int)threadIdx.x & 63;
    const int wid  = (int)threadIdx.x >> 6;
    const int o    = blockIdx.x * 4 + wid;
    if (o >= n_out) return;                       // wave-uniform exit

    const float ox = out_pos[3 * o];
    const float oy = out_pos[3 * o + 1];
    const float oz = out_pos[3 * o + 2];

    // Cell ranges from the true candidate interval [o-r-m, o+r+m]; margin m
    // covers fp slop on the d2<=r2 boundary. Worst span 4 cells/axis -> ncell<=64.
    const float m = 0.05f + 1e-4f;
    const int cxlo = max(0, (int)floorf((ox - m) * (float)GD));
    const int cxhi = min(GD - 1, (int)floorf((ox + m) * (float)GD));
    const int cylo = max(0, (int)floorf((oy - m) * (float)GD));
    const int cyhi = min(GD - 1, (int)floorf((oy + m) * (float)GD));
    const int czlo = max(0, (int)floorf((oz - m) * (float)GD));
    const int czhi = min(GD - 1, (int)floorf((oz + m) * (float)GD));
    const int nx = cxhi - cxlo + 1, ny = cyhi - cylo + 1, nz = czhi - czlo + 1;
    const int ncell = nx * ny * nz;               // <= 64

    // Lane l < ncell owns one cell: fetch its count (single gather).
    int cnt = 0, cellid = 0;
    if (lane < ncell) {
        int t = lane;
        const int dz = t % nz; t /= nz;
        const int dy = t % ny; t /= ny;
        const int dx = t;
        cellid = ((cxlo + dx) * GD + (cylo + dy)) * GD + (czlo + dz);
        cnt = min(counts[cellid], CAP);
    }

    // Wave-wide inclusive scan of counts.
    int incl = cnt;
#pragma unroll
    for (int d = 1; d < 64; d <<= 1) {
        const int v = __shfl_up(incl, d);
        if (lane >= d) incl += v;
    }
    const int T    = __shfl(incl, 63);            // total candidates
    const int excl = incl - cnt;

    float csum = 0.0f;
    float acc[MAXB];
#pragma unroll
    for (int b = 0; b < MAXB; ++b) acc[b] = 0.0f;

    for (int base = 0; base < T; base += 64) {    // typ. 1 pass (T ~ 55)
        const int t = base + lane;
        const bool act = t < T;
        // Binary search: smallest j with incl[j] > t (6 steps covers ncell<=64).
        int lo = 0, hi = ncell - 1;
#pragma unroll
        for (int it = 0; it < 6; ++it) {
            const int mid = (lo + hi) >> 1;
            const int v = __shfl(incl, mid);
            if (v > t) hi = mid; else lo = mid + 1;
        }
        const int j  = lo;
        const int cj = __shfl(cellid, j);
        const int ej = __shfl(excl, j);
        float4 cand = make_float4(1e9f, 1e9f, 1e9f, 0.0f);
        if (act) cand = bins[(size_t)cj * CAP + (t - ej)];
        // identical membership expression to validated rounds
        const float dx = ox - cand.x;
        const float dy = oy - cand.y;
        const float dz = oz - cand.z;
        const float d2 = dx * dx + dy * dy + dz * dz;
        if (d2 <= r2) {
            csum += 1.0f;
            const int idx = __float_as_int(cand.w);
            const float4* xv = (const float4*)(xT + (size_t)idx * MAXB);
            const float4 a = xv[0], b4 = xv[1];
            acc[0] += a.x;  acc[1] += a.y;  acc[2] += a.z;  acc[3] += a.w;
            acc[4] += b4.x; acc[5] += b4.y; acc[6] += b4.z; acc[7] += b4.w;
        }
    }

    // Butterfly reduce count + 8 batch sums across the wave.
#pragma unroll
    for (int d = 32; d >= 1; d >>= 1) {
        csum += __shfl_xor(csum, d);
#pragma unroll
        for (int b = 0; b < MAXB; ++b) acc[b] += __shfl_xor(acc[b], d);
    }
    if (lane == 0) {
        const float cc = (csum > 0.0f) ? csum : 1.0f;
        for (int b = 0; b < B; ++b)
            out[(size_t)b * n_out + o] = acc[b] / cc;
    }
}

// --- safety-net brute kernel (only if ws too small / B > 8) -----------------
__global__ void __launch_bounds__(TPB) brute_kernel(
    const float* __restrict__ x, const float* __restrict__ ip,
    const float* __restrict__ op, float* __restrict__ out,
    int B, int n_in, int n_out, float r2)
{
    const int o = blockIdx.x * TPB + (int)threadIdx.x;
    if (o >= n_out) return;
    const float ox = op[3 * o], oy = op[3 * o + 1], oz = op[3 * o + 2];
    float cnt = 0.0f, acc[MAXB];
#pragma unroll
    for (int b = 0; b < MAXB; ++b) acc[b] = 0.0f;
    for (int i = 0; i < n_in; ++i) {
        const float dx = ox - ip[3 * i];
        const float dy = oy - ip[3 * i + 1];
        const float dz = oz - ip[3 * i + 2];
        const float d2 = dx * dx + dy * dy + dz * dz;
        if (d2 <= r2) {
            cnt += 1.0f;
            for (int b = 0; b < B && b < MAXB; ++b) acc[b] += x[(size_t)b * n_in + i];
        }
    }
    const float cc = (cnt > 0.0f) ? cnt : 1.0f;
    for (int b = 0; b < B && b < MAXB; ++b)
        out[(size_t)b * n_out + o] = acc[b] / cc;
}

// --- host --------------------------------------------------------------------
extern "C" void kernel_launch(void* const* d_in, const int* in_sizes, int n_in_args,
                              void* d_out, int out_size, void* d_ws, size_t ws_size,
                              hipStream_t stream) {
    const float* x  = (const float*)d_in[0];
    const float* ip = (const float*)d_in[1];
    const float* op = (const float*)d_in[2];
    float* out = (float*)d_out;

    const int n_in  = in_sizes[1] / 3;
    const int n_out = in_sizes[2] / 3;
    const int B     = in_sizes[0] / n_in;
    const float r2  = (float)(0.05 * 0.05);

    const size_t counts_b = (size_t)NC * sizeof(int);            // 32 KB (16B-mult)
    const size_t bins_b   = (size_t)NC * CAP * sizeof(float4);   // 4 MB
    const size_t xT_b     = (size_t)n_in * MAXB * sizeof(float);
    const size_t need     = counts_b + bins_b + xT_b;

    if (B <= MAXB && ws_size >= need) {
        int*    counts = (int*)d_ws;
        float4* bins   = (float4*)((char*)d_ws + counts_b);
        float*  xT     = (float*)((char*)d_ws + counts_b + bins_b);

        hipMemsetAsync(counts, 0, counts_b, stream);
        bin_kernel<<<cdiv(n_in, TPB), TPB, 0, stream>>>(x, ip, counts, bins, xT,
                                                        B, n_in);
        query_kernel<<<cdiv(n_out, 4), TPB, 0, stream>>>(counts, bins, xT, op, out,
                                                         B, n_out, r2);
    } else {
        brute_kernel<<<cdiv(n_out, TPB), TPB, 0, stream>>>(x, ip, op, out,
                                                           B, n_in, n_out, r2);
    }
}

// Round 6
// 71.280 us; speedup vs baseline: 3.4266x; 1.0099x over previous
//
#include <hip/hip_runtime.h>

#define TPB   256
#define BINT  64     // bin kernel block size: 64-thr blocks spread over 256 CUs
#define MAXB  8
#define GD    20
#define NC    (GD * GD * GD)
#define CAP   32

static inline int cdiv(int a, int b) { return (a + b - 1) / b; }

// --- bin + transpose kernel --------------------------------------------------
// bins[cell][slot] = (px,py,pz, bitcast(i)); xT[i][0..7] = x[b][i] (0 for b>=B)
// 64-thread blocks: 16384 pts -> 256 blocks -> one latency-bound wave per CU.
__global__ void __launch_bounds__(BINT) bin_kernel(
    const float* __restrict__ x, const float* __restrict__ ip,
    int* __restrict__ counts, float4* __restrict__ bins,
    float* __restrict__ xT, int B, int n_in)
{
    const int i = blockIdx.x * BINT + (int)threadIdx.x;
    if (i >= n_in) return;
    const float px = ip[3 * i], py = ip[3 * i + 1], pz = ip[3 * i + 2];
    const int cx = min(GD - 1, max(0, (int)(px * (float)GD)));
    const int cy = min(GD - 1, max(0, (int)(py * (float)GD)));
    const int cz = min(GD - 1, max(0, (int)(pz * (float)GD)));
    const int cell = (cx * GD + cy) * GD + cz;
    const int slot = atomicAdd(counts + cell, 1);
    if (slot < CAP)   // P(count>32) ~ 0 at lambda=2.05; query clamps to CAP
        bins[(size_t)cell * CAP + slot] = make_float4(px, py, pz, __int_as_float(i));
    float v[MAXB];
#pragma unroll
    for (int b = 0; b < MAXB; ++b)
        v[b] = (b < B) ? x[(size_t)b * n_in + i] : 0.0f;
    float4* dst = (float4*)(xT + (size_t)i * MAXB);
    dst[0] = make_float4(v[0], v[1], v[2], v[3]);
    dst[1] = make_float4(v[4], v[5], v[6], v[7]);
}

// --- query kernel: one wave per output point --------------------------------
__global__ void __launch_bounds__(TPB) query_kernel(
    const int* __restrict__ counts, const float4* __restrict__ bins,
    const float* __restrict__ xT, const float* __restrict__ out_pos,
    float* __restrict__ out, int B, int n_out, float r2)
{
    const int lane = (int)threadIdx.x & 63;
    const int wid  = (int)threadIdx.x >> 6;
    const int o    = blockIdx.x * 4 + wid;
    if (o >= n_out) return;                       // wave-uniform exit

    const float ox = out_pos[3 * o];
    const float oy = out_pos[3 * o + 1];
    const float oz = out_pos[3 * o + 2];

    // Cell ranges from the true candidate interval [o-r-m, o+r+m]; margin m
    // covers fp slop on the d2<=r2 boundary (monotone fl(a*20) keeps binned
    // cells inside [cxlo,cxhi]). Worst span 4 cells/axis -> ncell<=64.
    const float m = 0.05f + 1e-4f;
    const int cxlo = max(0, (int)floorf((ox - m) * (float)GD));
    const int cxhi = min(GD - 1, (int)floorf((ox + m) * (float)GD));
    const int cylo = max(0, (int)floorf((oy - m) * (float)GD));
    const int cyhi = min(GD - 1, (int)floorf((oy + m) * (float)GD));
    const int czlo = max(0, (int)floorf((oz - m) * (float)GD));
    const int czhi = min(GD - 1, (int)floorf((oz + m) * (float)GD));
    const int nx = cxhi - cxlo + 1, ny = cyhi - cylo + 1, nz = czhi - czlo + 1;
    const int ncell = nx * ny * nz;               // <= 64

    // Lane l < ncell owns one cell: fetch its count (single gather).
    int cnt = 0, cellid = 0;
    if (lane < ncell) {
        int t = lane;
        const int dz = t % nz; t /= nz;
        const int dy = t % ny; t /= ny;
        const int dx = t;
        cellid = ((cxlo + dx) * GD + (cylo + dy)) * GD + (czlo + dz);
        cnt = min(counts[cellid], CAP);
    }

    // Wave-wide inclusive scan of counts.
    int incl = cnt;
#pragma unroll
    for (int d = 1; d < 64; d <<= 1) {
        const int v = __shfl_up(incl, d);
        if (lane >= d) incl += v;
    }
    const int T    = __shfl(incl, 63);            // total candidates
    const int excl = incl - cnt;

    float csum = 0.0f;
    float acc[MAXB];
#pragma unroll
    for (int b = 0; b < MAXB; ++b) acc[b] = 0.0f;

    for (int base = 0; base < T; base += 64) {    // typ. 1 pass (T ~ 55)
        const int t = base + lane;
        const bool act = t < T;
        // Binary search: smallest j with incl[j] > t (6 steps covers ncell<=64).
        int lo = 0, hi = ncell - 1;
#pragma unroll
        for (int it = 0; it < 6; ++it) {
            const int mid = (lo + hi) >> 1;
            const int v = __shfl(incl, mid);
            if (v > t) hi = mid; else lo = mid + 1;
        }
        const int j  = lo;
        const int cj = __shfl(cellid, j);
        const int ej = __shfl(excl, j);
        float4 cand = make_float4(1e9f, 1e9f, 1e9f, 0.0f);
        if (act) cand = bins[(size_t)cj * CAP + (t - ej)];
        // identical membership expression to validated rounds
        const float dx = ox - cand.x;
        const float dy = oy - cand.y;
        const float dz = oz - cand.z;
        const float d2 = dx * dx + dy * dy + dz * dz;
        if (d2 <= r2) {
            csum += 1.0f;
            const int idx = __float_as_int(cand.w);
            const float4* xv = (const float4*)(xT + (size_t)idx * MAXB);
            const float4 a = xv[0], b4 = xv[1];
            acc[0] += a.x;  acc[1] += a.y;  acc[2] += a.z;  acc[3] += a.w;
            acc[4] += b4.x; acc[5] += b4.y; acc[6] += b4.z; acc[7] += b4.w;
        }
    }

    // Butterfly reduce count + 8 batch sums across the wave.
#pragma unroll
    for (int d = 32; d >= 1; d >>= 1) {
        csum += __shfl_xor(csum, d);
#pragma unroll
        for (int b = 0; b < MAXB; ++b) acc[b] += __shfl_xor(acc[b], d);
    }
    if (lane == 0) {
        const float cc = (csum > 0.0f) ? csum : 1.0f;
        for (int b = 0; b < B; ++b)
            out[(size_t)b * n_out + o] = acc[b] / cc;
    }
}

// --- safety-net brute kernel (only if ws too small / B > 8) -----------------
__global__ void __launch_bounds__(TPB) brute_kernel(
    const float* __restrict__ x, const float* __restrict__ ip,
    const float* __restrict__ op, float* __restrict__ out,
    int B, int n_in, int n_out, float r2)
{
    const int o = blockIdx.x * TPB + (int)threadIdx.x;
    if (o >= n_out) return;
    const float ox = op[3 * o], oy = op[3 * o + 1], oz = op[3 * o + 2];
    float cnt = 0.0f, acc[MAXB];
#pragma unroll
    for (int b = 0; b < MAXB; ++b) acc[b] = 0.0f;
    for (int i = 0; i < n_in; ++i) {
        const float dx = ox - ip[3 * i];
        const float dy = oy - ip[3 * i + 1];
        const float dz = oz - ip[3 * i + 2];
        const float d2 = dx * dx + dy * dy + dz * dz;
        if (d2 <= r2) {
            cnt += 1.0f;
            for (int b = 0; b < B && b < MAXB; ++b) acc[b] += x[(size_t)b * n_in + i];
        }
    }
    const float cc = (cnt > 0.0f) ? cnt : 1.0f;
    for (int b = 0; b < B && b < MAXB; ++b)
        out[(size_t)b * n_out + o] = acc[b] / cc;
}

// --- host --------------------------------------------------------------------
extern "C" void kernel_launch(void* const* d_in, const int* in_sizes, int n_in_args,
                              void* d_out, int out_size, void* d_ws, size_t ws_size,
                              hipStream_t stream) {
    const float* x  = (const float*)d_in[0];
    const float* ip = (const float*)d_in[1];
    const float* op = (const float*)d_in[2];
    float* out = (float*)d_out;

    const int n_in  = in_sizes[1] / 3;
    const int n_out = in_sizes[2] / 3;
    const int B     = in_sizes[0] / n_in;
    const float r2  = (float)(0.05 * 0.05);

    const size_t counts_b = (size_t)NC * sizeof(int);            // 32 KB
    const size_t bins_b   = (size_t)NC * CAP * sizeof(float4);   // 4 MB
    const size_t xT_b     = (size_t)n_in * MAXB * sizeof(float);
    const size_t need     = counts_b + bins_b + xT_b;

    if (B <= MAXB && ws_size >= need) {
        int*    counts = (int*)d_ws;
        float4* bins   = (float4*)((char*)d_ws + counts_b);
        float*  xT     = (float*)((char*)d_ws + counts_b + bins_b);

        hipMemsetAsync(counts, 0, counts_b, stream);
        bin_kernel<<<cdiv(n_in, BINT), BINT, 0, stream>>>(x, ip, counts, bins, xT,
                                                          B, n_in);
        query_kernel<<<cdiv(n_out, 4), TPB, 0, stream>>>(counts, bins, xT, op, out,
                                                         B, n_out, r2);
    } else {
        brute_kernel<<<cdiv(n_out, TPB), TPB, 0, stream>>>(x, ip, op, out,
                                                           B, n_in, n_out, r2);
    }
}